// Round 5
// baseline (157.392 us; speedup 1.0000x reference)
//
#include <hip/hip_runtime.h>
#include <math.h>

#define ALPHA   0.99f
#define ONE_M   0.01f     // 1 - ALPHA
#define T_LEN   4000
#define F_DIM   64
#define NCHUNK  50
#define CHUNK_L 80        // T_LEN / NCHUNK
#define NG      16        // float4 groups per row = F_DIM/4 (full 256B rows)
#define NTHREADS (NCHUNK * NG)   // 800
#define PF      4         // float4 loads per pipeline stage
#define NGRP    (CHUNK_L / PF)   // 20 groups (even)

typedef float f32x4 __attribute__((ext_vector_type(4)));

// Exact chunked scan, per (b, f):
//   mu_L  = a^L mu_0 + m_L                     (m: EMA of x within chunk)
//   var_L = a^L var_0 + SP + c2*SU*mu_0 + R*mu_0^2
//   SP = EMA of u^2, SU = sum of u (u = x - m), c2 = -2(1-a)a^L, R = a^{L+1}(1-a^L)
//
// Depth-2 software pipeline: group k+1's loads are issued BEFORE group k's
// compute, so the vmcnt wait lands after ~220 cy of FMA work instead of
// immediately after issue. Alternating va/vb buffers avoid a reg-copy.
__global__ __launch_bounds__(NTHREADS, 4)
void erbnorm_kernel(const float* __restrict__ x, float* __restrict__ out, float aL) {
    const int b   = blockIdx.x;
    const int tid = threadIdx.x;
    const int c   = tid >> 4;          // chunk 0..49
    const int g   = tid & 15;          // float4 group 0..15

    __shared__ float s_m [NCHUNK][F_DIM];   // m  -> entering mu (after combine)
    __shared__ float s_sp[NCHUNK][F_DIM];   // SP -> entering var
    __shared__ float s_su[NCHUNK][F_DIM];   // SU

    const size_t base = ((size_t)b * T_LEN + (size_t)c * CHUNK_L) * F_DIM + g * 4;
    const float* xp = x + base;

    // ---- pass 1: per-chunk transition coefficients (4 features/thread) ----
    {
        f32x4 m = 0.f, sp = 0.f, su = 0.f;
        f32x4 va[PF], vb[PF];
        const float* p = xp;

#pragma unroll
        for (int j = 0; j < PF; ++j)
            va[j] = *(const f32x4*)(p + (size_t)j * F_DIM);

        for (int gg = 0; gg < NGRP - 2; gg += 2) {
#pragma unroll
            for (int j = 0; j < PF; ++j)
                vb[j] = *(const f32x4*)(p + (size_t)(PF + j) * F_DIM);
#pragma unroll
            for (int j = 0; j < PF; ++j) {
                f32x4 xi = va[j];
                m = ALPHA * m + ONE_M * xi;
                f32x4 u = xi - m;
                sp = ALPHA * sp + ONE_M * (u * u);
                su = su + u;
            }
            p += (size_t)(2 * PF) * F_DIM;
#pragma unroll
            for (int j = 0; j < PF; ++j)
                va[j] = *(const f32x4*)(p + (size_t)j * F_DIM);
#pragma unroll
            for (int j = 0; j < PF; ++j) {
                f32x4 xi = vb[j];
                m = ALPHA * m + ONE_M * xi;
                f32x4 u = xi - m;
                sp = ALPHA * sp + ONE_M * (u * u);
                su = su + u;
            }
        }
        // epilogue: va holds group NGRP-2; load+consume last group
#pragma unroll
        for (int j = 0; j < PF; ++j)
            vb[j] = *(const f32x4*)(p + (size_t)(PF + j) * F_DIM);
#pragma unroll
        for (int j = 0; j < PF; ++j) {
            f32x4 xi = va[j];
            m = ALPHA * m + ONE_M * xi;
            f32x4 u = xi - m;
            sp = ALPHA * sp + ONE_M * (u * u);
            su = su + u;
        }
#pragma unroll
        for (int j = 0; j < PF; ++j) {
            f32x4 xi = vb[j];
            m = ALPHA * m + ONE_M * xi;
            f32x4 u = xi - m;
            sp = ALPHA * sp + ONE_M * (u * u);
            su = su + u;
        }
        *(f32x4*)&s_m [c][g * 4] = m;
        *(f32x4*)&s_sp[c][g * 4] = sp;
        *(f32x4*)&s_su[c][g * 4] = su;
    }
    __syncthreads();

    // ---- combine: serial chain over 50 chunks, one thread per feature ----
    if (tid < F_DIM) {
        const float step = -30.f / 63.f;
        float mu  = -60.f + (float)tid * step;
        float var = 1600.f;
        const float R  = ALPHA * aL * (1.f - aL);   // a^(L+1)(1-a^L)
        const float c2 = -2.f * ONE_M * aL;         // -2(1-a)a^L
        for (int cc = 0; cc < NCHUNK; ++cc) {
            float m  = s_m [cc][tid];
            float sp = s_sp[cc][tid];
            float su = s_su[cc][tid];
            s_m [cc][tid] = mu;                     // entering state for pass 2
            s_sp[cc][tid] = var;
            float mu_n = aL * mu + m;
            var = aL * var + sp + (c2 * su) * mu + R * mu * mu;
            mu = mu_n;
        }
    }
    __syncthreads();

    // ---- pass 2: replay with exact entering state, emit outputs ----
    {
        f32x4 mu  = *(const f32x4*)&s_m [c][g * 4];
        f32x4 var = *(const f32x4*)&s_sp[c][g * 4];
        f32x4 va[PF], vb[PF];
        const float* p = xp;
        float* op = out + base;

#pragma unroll
        for (int j = 0; j < PF; ++j)
            va[j] = *(const f32x4*)(p + (size_t)j * F_DIM);

        for (int gg = 0; gg < NGRP - 2; gg += 2) {
#pragma unroll
            for (int j = 0; j < PF; ++j)
                vb[j] = *(const f32x4*)(p + (size_t)(PF + j) * F_DIM);
#pragma unroll
            for (int j = 0; j < PF; ++j) {
                f32x4 xi = va[j];
                mu = ALPHA * mu + ONE_M * xi;
                f32x4 d = xi - mu;
                var = ALPHA * var + ONE_M * (d * d);
                f32x4 o;
                o[0] = d[0] * __builtin_amdgcn_rsqf(var[0]);
                o[1] = d[1] * __builtin_amdgcn_rsqf(var[1]);
                o[2] = d[2] * __builtin_amdgcn_rsqf(var[2]);
                o[3] = d[3] * __builtin_amdgcn_rsqf(var[3]);
                *(f32x4*)(op + (size_t)(gg * PF + j) * F_DIM) = o;
            }
            p += (size_t)(2 * PF) * F_DIM;
#pragma unroll
            for (int j = 0; j < PF; ++j)
                va[j] = *(const f32x4*)(p + (size_t)j * F_DIM);
#pragma unroll
            for (int j = 0; j < PF; ++j) {
                f32x4 xi = vb[j];
                mu = ALPHA * mu + ONE_M * xi;
                f32x4 d = xi - mu;
                var = ALPHA * var + ONE_M * (d * d);
                f32x4 o;
                o[0] = d[0] * __builtin_amdgcn_rsqf(var[0]);
                o[1] = d[1] * __builtin_amdgcn_rsqf(var[1]);
                o[2] = d[2] * __builtin_amdgcn_rsqf(var[2]);
                o[3] = d[3] * __builtin_amdgcn_rsqf(var[3]);
                *(f32x4*)(op + (size_t)((gg + 1) * PF + j) * F_DIM) = o;
            }
        }
        // epilogue: groups NGRP-2 (in va) and NGRP-1
#pragma unroll
        for (int j = 0; j < PF; ++j)
            vb[j] = *(const f32x4*)(p + (size_t)(PF + j) * F_DIM);
#pragma unroll
        for (int j = 0; j < PF; ++j) {
            f32x4 xi = va[j];
            mu = ALPHA * mu + ONE_M * xi;
            f32x4 d = xi - mu;
            var = ALPHA * var + ONE_M * (d * d);
            f32x4 o;
            o[0] = d[0] * __builtin_amdgcn_rsqf(var[0]);
            o[1] = d[1] * __builtin_amdgcn_rsqf(var[1]);
            o[2] = d[2] * __builtin_amdgcn_rsqf(var[2]);
            o[3] = d[3] * __builtin_amdgcn_rsqf(var[3]);
            *(f32x4*)(op + (size_t)((NGRP - 2) * PF + j) * F_DIM) = o;
        }
#pragma unroll
        for (int j = 0; j < PF; ++j) {
            f32x4 xi = vb[j];
            mu = ALPHA * mu + ONE_M * xi;
            f32x4 d = xi - mu;
            var = ALPHA * var + ONE_M * (d * d);
            f32x4 o;
            o[0] = d[0] * __builtin_amdgcn_rsqf(var[0]);
            o[1] = d[1] * __builtin_amdgcn_rsqf(var[1]);
            o[2] = d[2] * __builtin_amdgcn_rsqf(var[2]);
            o[3] = d[3] * __builtin_amdgcn_rsqf(var[3]);
            *(f32x4*)(op + (size_t)((NGRP - 1) * PF + j) * F_DIM) = o;
        }
    }
}

extern "C" void kernel_launch(void* const* d_in, const int* in_sizes, int n_in,
                              void* d_out, int out_size, void* d_ws, size_t ws_size,
                              hipStream_t stream) {
    const float* x = (const float*)d_in[0];
    float* out = (float*)d_out;
    const float aL = (float)pow(0.99, (double)CHUNK_L);  // a^L
    hipLaunchKernelGGL(erbnorm_kernel, dim3(256), dim3(NTHREADS), 0, stream,
                       x, out, aL);
}